// Round 4
// baseline (59.574 us; speedup 1.0000x reference)
//
#include <hip/hip_runtime.h>
#include <math.h>

#define N_PTS  65536
#define N_CTR  1024
#define CHUNK  64           // centers per block -> 16 chunks
#define PPT    4            // points per thread (state fits in <64 VGPRs)
#define PPB    (256 * PPT)  // 1024 points per block

#if __has_builtin(__builtin_amdgcn_exp2f)
#define EXP2(v) __builtin_amdgcn_exp2f(v)
#else
#define EXP2(v) exp2f(v)
#endif

// Folded per-center constants, computed once by prep_kernel into d_ws:
//   RA[j] = (zb, zc, zd, ze)   exponent polynomial coeffs (log2e folded)
//   RB[j] = (za, k0, k1, k2)   poly offset + accumulation coeffs
//   RC[j] = k3                 (set 0 only)
// s = za + zb*x + zc*x^2 + zd*y + ze*y^2 ;  e = exp2(s)
// set0: ux = x*sum(k0 e)+sum(k1 e), uy = y*sum(k2 e)+sum(k3 e)
// set1: P  = sum(k0 e),  Px = x*sum(k1 e)+sum(k2 e)
// set2: Q  = sum(k0 e),  Qy = y*sum(k1 e)+sum(k2 e)

__global__ __launch_bounds__(256) void prep_kernel(
    const float* __restrict__ h0, const float* __restrict__ c0, const float* __restrict__ w0,
    const float* __restrict__ h1, const float* __restrict__ c1, const float* __restrict__ w1,
    const float* __restrict__ h2, const float* __restrict__ c2, const float* __restrict__ w2,
    float4* __restrict__ RA, float4* __restrict__ RB, float* __restrict__ RC)
{
    const int idx = blockIdx.x * 256 + threadIdx.x;
    if (idx >= 3 * N_CTR) return;
    const int set = idx >> 10;
    const int j   = idx & (N_CTR - 1);

    const float*  h = (set == 0) ? h0 : ((set == 1) ? h1 : h2);
    const float2* c = (const float2*)((set == 0) ? c0 : ((set == 1) ? c1 : c2));
    const float2* w = (const float2*)((set == 0) ? w0 : ((set == 1) ? w1 : w2));

    const float LOG2E = 1.4426950408889634f;
    float2 cj = c[j];
    float2 wj = w[j];
    float  hh = h[j];
    float d1 = wj.x * wj.x;
    float d2 = wj.y * wj.y;
    float zb =  2.f * cj.x * d1 * LOG2E;
    float zc = -d1 * LOG2E;
    float zd =  2.f * cj.y * d2 * LOG2E;
    float ze = -d2 * LOG2E;
    float za = -(cj.x * cj.x * d1 + cj.y * cj.y * d2) * LOG2E;
    float k0, k1, k2, k3;
    if (set == 0) {
        k0 = -2.f * hh * d1;  k1 = 2.f * hh * d1 * cj.x;
        k2 = -2.f * hh * d2;  k3 = 2.f * hh * d2 * cj.y;
    } else if (set == 1) {
        k0 = hh;  k1 = -2.f * hh * d1;  k2 = 2.f * hh * d1 * cj.x;  k3 = 0.f;
    } else {
        k0 = hh;  k1 = -2.f * hh * d2;  k2 = 2.f * hh * d2 * cj.y;  k3 = 0.f;
    }
    RA[idx] = make_float4(zb, zc, zd, ze);
    RB[idx] = make_float4(za, k0, k1, k2);
    RC[idx] = k3;
}

__global__ __launch_bounds__(256) void srbf_main(
    const float* __restrict__ x,
    const float4* __restrict__ RA,
    const float4* __restrict__ RB,
    const float*  __restrict__ RC,
    float* __restrict__ out)
{
    const int bid   = blockIdx.x;
    const int set   = bid >> 10;           // 1024 blocks per set
    const int r     = bid & 1023;
    const int chunk = r >> 6;              // 16 chunks of 64 centers
    const int pblk  = r & 63;              // 64 point-blocks of 1024 points
    const int tid   = threadIdx.x;
    const int cbase = set * N_CTR + chunk * CHUNK;

    const int base = pblk * PPB + tid;
    float X[PPT], Y[PPT], X2[PPT], Y2[PPT];
    #pragma unroll
    for (int p = 0; p < PPT; ++p) {
        float2 q = ((const float2*)x)[base + p * 256];
        X[p] = q.x;  Y[p] = q.y;
        X2[p] = q.x * q.x;  Y2[p] = q.y * q.y;
    }

    if (set == 0) {
        float A0[PPT], A1[PPT], A2[PPT], A3[PPT];
        #pragma unroll
        for (int p = 0; p < PPT; ++p) { A0[p] = A1[p] = A2[p] = A3[p] = 0.f; }

        #pragma unroll 4
        for (int jj = 0; jj < CHUNK; ++jj) {
            const float4 A = RA[cbase + jj];   // uniform -> s_load
            const float4 B = RB[cbase + jj];
            const float  k3 = RC[cbase + jj];
            #pragma unroll
            for (int p = 0; p < PPT; ++p) {
                float s = fmaf(X[p],  A.x, B.x);
                s       = fmaf(X2[p], A.y, s);
                s       = fmaf(Y[p],  A.z, s);
                s       = fmaf(Y2[p], A.w, s);
                float e = EXP2(s);
                A0[p] = fmaf(B.y, e, A0[p]);
                A1[p] = fmaf(B.z, e, A1[p]);
                A2[p] = fmaf(B.w, e, A2[p]);
                A3[p] = fmaf(k3,  e, A3[p]);
            }
        }
        #pragma unroll
        for (int p = 0; p < PPT; ++p) {
            const int i = base + p * 256;
            atomicAdd(&out[i],         fmaf(X[p], A0[p], A1[p]));   // ux
            atomicAdd(&out[N_PTS + i], fmaf(Y[p], A2[p], A3[p]));   // uy
        }
    } else {
        float A0[PPT], A1[PPT], A2[PPT];
        #pragma unroll
        for (int p = 0; p < PPT; ++p) { A0[p] = A1[p] = A2[p] = 0.f; }

        #pragma unroll 4
        for (int jj = 0; jj < CHUNK; ++jj) {
            const float4 A = RA[cbase + jj];
            const float4 B = RB[cbase + jj];
            #pragma unroll
            for (int p = 0; p < PPT; ++p) {
                float s = fmaf(X[p],  A.x, B.x);
                s       = fmaf(X2[p], A.y, s);
                s       = fmaf(Y[p],  A.z, s);
                s       = fmaf(Y2[p], A.w, s);
                float e = EXP2(s);
                A0[p] = fmaf(B.y, e, A0[p]);
                A1[p] = fmaf(B.z, e, A1[p]);
                A2[p] = fmaf(B.w, e, A2[p]);
            }
        }
        float* o = out + (size_t)set * 2 * N_PTS;
        #pragma unroll
        for (int p = 0; p < PPT; ++p) {
            const int i = base + p * 256;
            const float g = (set == 1) ? X[p] : Y[p];
            atomicAdd(&o[i],         A0[p]);                  // P or Q
            atomicAdd(&o[N_PTS + i], fmaf(g, A1[p], A2[p]));  // Px or Qy
        }
    }
}

extern "C" void kernel_launch(void* const* d_in, const int* in_sizes, int n_in,
                              void* d_out, int out_size, void* d_ws, size_t ws_size,
                              hipStream_t stream) {
    const float* x  = (const float*)d_in[0];
    const float* h1 = (const float*)d_in[1];
    const float* c1 = (const float*)d_in[2];
    const float* w1 = (const float*)d_in[3];
    const float* h2 = (const float*)d_in[4];
    const float* c2 = (const float*)d_in[5];
    const float* w2 = (const float*)d_in[6];
    const float* h3 = (const float*)d_in[7];
    const float* c3 = (const float*)d_in[8];
    const float* w3 = (const float*)d_in[9];

    char* ws = (char*)d_ws;
    float4* RA = (float4*)(ws);                 // 3*1024*16 = 49152 B
    float4* RB = (float4*)(ws + 49152);         // 49152 B
    float*  RC = (float*) (ws + 98304);         // 12288 B

    hipMemsetAsync(d_out, 0, (size_t)out_size * sizeof(float), stream);

    prep_kernel<<<dim3(12), dim3(256), 0, stream>>>(
        h1, c1, w1, h2, c2, w2, h3, c3, w3, RA, RB, RC);

    // 3 sets x 16 center-chunks x 64 point-blocks = 3072 blocks
    srbf_main<<<dim3(3072), dim3(256), 0, stream>>>(x, RA, RB, RC, (float*)d_out);
}

// Round 5
// 57.142 us; speedup vs baseline: 1.0426x; 1.0426x over previous
//
#include <hip/hip_runtime.h>
#include <math.h>

#define N_PTS  65536
#define N_CTR  1024
#define CHUNK  64           // centers per block -> 16 chunks
#define PPT    4            // points per thread
#define PPB    (256 * PPT)  // 1024 points per block

#if __has_builtin(__builtin_amdgcn_exp2f)
#define EXP2(v) __builtin_amdgcn_exp2f(v)
#else
#define EXP2(v) exp2f(v)
#endif

// Folded per-center constants (prep_kernel -> d_ws):
//   RA[j] = (zb, zc, zd, ze)   exponent poly coeffs (log2e folded)
//   RB[j] = (za, k0, k1, k2)
//   RC[j] = k3                 (set 0 only)
// Horner: s = (za + x*(zb + zc*x)) + y*(zd + ze*y) ; e = exp2(s)
// set0: ux = x*S(k0 e)+S(k1 e), uy = y*S(k2 e)+S(k3 e)
// set1: P  = S(k0 e),  Px = x*S(k1 e)+S(k2 e)
// set2: Q  = S(k0 e),  Qy = y*S(k1 e)+S(k2 e)

__global__ __launch_bounds__(256) void prep_kernel(
    const float* __restrict__ h0, const float* __restrict__ c0, const float* __restrict__ w0,
    const float* __restrict__ h1, const float* __restrict__ c1, const float* __restrict__ w1,
    const float* __restrict__ h2, const float* __restrict__ c2, const float* __restrict__ w2,
    float4* __restrict__ RA, float4* __restrict__ RB, float* __restrict__ RC,
    float4* __restrict__ out_zero)
{
    const int idx = blockIdx.x * 256 + threadIdx.x;

    // fused output zeroing: 3072 threads x 32 float4 = 393216 floats
    {
        float4 z = make_float4(0.f, 0.f, 0.f, 0.f);
        float4* o = out_zero + idx * 32;
        #pragma unroll
        for (int t = 0; t < 32; ++t) o[t] = z;
    }

    if (idx >= 3 * N_CTR) return;
    const int set = idx >> 10;
    const int j   = idx & (N_CTR - 1);

    const float*  h = (set == 0) ? h0 : ((set == 1) ? h1 : h2);
    const float2* c = (const float2*)((set == 0) ? c0 : ((set == 1) ? c1 : c2));
    const float2* w = (const float2*)((set == 0) ? w0 : ((set == 1) ? w1 : w2));

    const float LOG2E = 1.4426950408889634f;
    float2 cj = c[j];
    float2 wj = w[j];
    float  hh = h[j];
    float d1 = wj.x * wj.x;
    float d2 = wj.y * wj.y;
    float zb =  2.f * cj.x * d1 * LOG2E;
    float zc = -d1 * LOG2E;
    float zd =  2.f * cj.y * d2 * LOG2E;
    float ze = -d2 * LOG2E;
    float za = -(cj.x * cj.x * d1 + cj.y * cj.y * d2) * LOG2E;
    float k0, k1, k2, k3;
    if (set == 0) {
        k0 = -2.f * hh * d1;  k1 = 2.f * hh * d1 * cj.x;
        k2 = -2.f * hh * d2;  k3 = 2.f * hh * d2 * cj.y;
    } else if (set == 1) {
        k0 = hh;  k1 = -2.f * hh * d1;  k2 = 2.f * hh * d1 * cj.x;  k3 = 0.f;
    } else {
        k0 = hh;  k1 = -2.f * hh * d2;  k2 = 2.f * hh * d2 * cj.y;  k3 = 0.f;
    }
    RA[idx] = make_float4(zb, zc, zd, ze);
    RB[idx] = make_float4(za, k0, k1, k2);
    RC[idx] = k3;
}

__global__ __launch_bounds__(256, 8) void srbf_main(
    const float* __restrict__ x,
    const float4* __restrict__ RA,
    const float4* __restrict__ RB,
    const float*  __restrict__ RC,
    float* __restrict__ out)
{
    const int bid   = blockIdx.x;
    const int set   = bid >> 10;           // 1024 blocks per set
    const int r     = bid & 1023;
    const int chunk = r >> 6;              // 16 chunks of 64 centers
    const int pblk  = r & 63;              // 64 point-blocks of 1024 points
    const int tid   = threadIdx.x;
    const int cbase = set * N_CTR + chunk * CHUNK;

    const int base = pblk * PPB + tid;
    float X[PPT], Y[PPT];
    #pragma unroll
    for (int p = 0; p < PPT; ++p) {
        float2 q = ((const float2*)x)[base + p * 256];
        X[p] = q.x;  Y[p] = q.y;
    }

    if (set == 0) {
        float A0[PPT], A1[PPT], A2[PPT], A3[PPT];
        #pragma unroll
        for (int p = 0; p < PPT; ++p) { A0[p] = A1[p] = A2[p] = A3[p] = 0.f; }

        #pragma unroll 4
        for (int jj = 0; jj < CHUNK; ++jj) {
            const float4 A  = RA[cbase + jj];   // uniform -> s_load (SGPR)
            const float4 B  = RB[cbase + jj];
            const float  k3 = RC[cbase + jj];
            float e[PPT];
            #pragma unroll
            for (int p = 0; p < PPT; ++p) {
                float t1 = fmaf(X[p], A.y, A.x);   // zb + zc*x
                float t2 = fmaf(X[p], t1,  B.x);   // za + x*(...)
                float t3 = fmaf(Y[p], A.w, A.z);   // zd + ze*y
                float s  = fmaf(Y[p], t3,  t2);
                e[p] = EXP2(s);
            }
            #pragma unroll
            for (int p = 0; p < PPT; ++p) {
                A0[p] = fmaf(B.y, e[p], A0[p]);
                A1[p] = fmaf(B.z, e[p], A1[p]);
                A2[p] = fmaf(B.w, e[p], A2[p]);
                A3[p] = fmaf(k3,  e[p], A3[p]);
            }
        }
        #pragma unroll
        for (int p = 0; p < PPT; ++p) {
            const int i = base + p * 256;
            atomicAdd(&out[i],         fmaf(X[p], A0[p], A1[p]));   // ux
            atomicAdd(&out[N_PTS + i], fmaf(Y[p], A2[p], A3[p]));   // uy
        }
    } else {
        float A0[PPT], A1[PPT], A2[PPT];
        #pragma unroll
        for (int p = 0; p < PPT; ++p) { A0[p] = A1[p] = A2[p] = 0.f; }

        #pragma unroll 4
        for (int jj = 0; jj < CHUNK; ++jj) {
            const float4 A = RA[cbase + jj];
            const float4 B = RB[cbase + jj];
            float e[PPT];
            #pragma unroll
            for (int p = 0; p < PPT; ++p) {
                float t1 = fmaf(X[p], A.y, A.x);
                float t2 = fmaf(X[p], t1,  B.x);
                float t3 = fmaf(Y[p], A.w, A.z);
                float s  = fmaf(Y[p], t3,  t2);
                e[p] = EXP2(s);
            }
            #pragma unroll
            for (int p = 0; p < PPT; ++p) {
                A0[p] = fmaf(B.y, e[p], A0[p]);
                A1[p] = fmaf(B.z, e[p], A1[p]);
                A2[p] = fmaf(B.w, e[p], A2[p]);
            }
        }
        float* o = out + (size_t)set * 2 * N_PTS;
        #pragma unroll
        for (int p = 0; p < PPT; ++p) {
            const int i = base + p * 256;
            const float g = (set == 1) ? X[p] : Y[p];
            atomicAdd(&o[i],         A0[p]);                  // P or Q
            atomicAdd(&o[N_PTS + i], fmaf(g, A1[p], A2[p]));  // Px or Qy
        }
    }
}

extern "C" void kernel_launch(void* const* d_in, const int* in_sizes, int n_in,
                              void* d_out, int out_size, void* d_ws, size_t ws_size,
                              hipStream_t stream) {
    const float* x  = (const float*)d_in[0];
    const float* h1 = (const float*)d_in[1];
    const float* c1 = (const float*)d_in[2];
    const float* w1 = (const float*)d_in[3];
    const float* h2 = (const float*)d_in[4];
    const float* c2 = (const float*)d_in[5];
    const float* w2 = (const float*)d_in[6];
    const float* h3 = (const float*)d_in[7];
    const float* c3 = (const float*)d_in[8];
    const float* w3 = (const float*)d_in[9];

    char* ws = (char*)d_ws;
    float4* RA = (float4*)(ws);                 // 3*1024*16 = 49152 B
    float4* RB = (float4*)(ws + 49152);         // 49152 B
    float*  RC = (float*) (ws + 98304);         // 12288 B

    // prep folds constants AND zeroes d_out (no separate memset dispatch)
    prep_kernel<<<dim3(12), dim3(256), 0, stream>>>(
        h1, c1, w1, h2, c2, w2, h3, c3, w3, RA, RB, RC, (float4*)d_out);

    // 3 sets x 16 center-chunks x 64 point-blocks = 3072 blocks
    srbf_main<<<dim3(3072), dim3(256), 0, stream>>>(x, RA, RB, RC, (float*)d_out);
}